// Round 8
// baseline (9159.547 us; speedup 1.0000x reference)
//
#include <hip/hip_runtime.h>
#include <hip/hip_bf16.h>
#include <cstdint>

#define NN 50000
#define NEDGE 320000

#define K_F32 0
#define K_BF16 1
#define K_IN 2   // resolve via flags[0]

typedef __attribute__((ext_vector_type(8))) short bf16x8;
typedef __attribute__((ext_vector_type(4))) float f32x4;

// ---------- helpers ----------
__device__ __forceinline__ float bf2f(unsigned short u) {
  return __uint_as_float(((unsigned)u) << 16);
}
__device__ __forceinline__ unsigned short f2bf(float f) {
  unsigned u = __float_as_uint(f);
  unsigned r = ((u >> 16) & 1u) + 0x7FFFu;   // RNE
  return (unsigned short)((u + r) >> 16);
}
__device__ __forceinline__ float load1f(const void* p, size_t i, int isbf) {
  return isbf ? bf2f(((const unsigned short*)p)[i]) : ((const float*)p)[i];
}
__device__ __forceinline__ int maskAt(const void* m, int i, int u8) {
  return u8 ? (int)((const unsigned char*)m)[i] : ((const int*)m)[i];
}

// ---------- sniff dtypes (flags[0]=floats bf16, [1]=masks u8, [2]=edges i64) ----------
__global__ void sniff_kernel(const void* bg, const void* mask, const void* ei, int* flags) {
  if (threadIdx.x == 0 && blockIdx.x == 0) {
    unsigned w = *(const unsigned*)bg;
    flags[0] = (w == 0x3F800000u) ? 0 : 1;
    const unsigned char* mb = (const unsigned char*)mask;
    int u8 = 0;
    for (int i = 0; i < 1024; ++i)
      if ((i & 3) && mb[i]) { u8 = 1; break; }
    flags[1] = u8;
    const int* ew = (const int*)ei;
    int i64 = 1;
    for (int i = 0; i < 256; ++i)
      if (ew[2 * i + 1] != 0) { i64 = 0; break; }
    flags[2] = i64;
  }
}

__global__ void diag_kernel(void* out, float v) {
  if (threadIdx.x == 0 && blockIdx.x == 0) ((unsigned short*)out)[0] = f2bf(v);
}

// ---------- weight transpose: Wt[n][k] = bf16(W[k][n]) ----------
__global__ void transpose_w(const void* __restrict__ W, const int* __restrict__ flags,
                            unsigned short* __restrict__ Wt, int K, int Ko) {
  int idx = blockIdx.x * 256 + threadIdx.x;
  if (idx >= K * Ko) return;
  int n = idx / K, k = idx - n * K;
  Wt[idx] = f2bf(load1f(W, (size_t)k * Ko + n, flags[0]));
}

// ---------- CSR build ----------
__global__ void csr_hist(const void* __restrict__ eip, const int* __restrict__ flags,
                         int* __restrict__ deg) {
  int e = blockIdx.x * 256 + threadIdx.x;
  if (e >= NEDGE) return;
  int d = flags[2] ? (int)((const long long*)eip)[NEDGE + e] : ((const int*)eip)[NEDGE + e];
  atomicAdd(deg + d, 1);
}

__global__ void scan1(const int* __restrict__ deg, int* __restrict__ rowptr,
                      int* __restrict__ bsum) {
  __shared__ int sm[256];
  int t = threadIdx.x, i = blockIdx.x * 256 + t;
  int v = (i < NN) ? deg[i] : 0;
  sm[t] = v; __syncthreads();
  for (int o = 1; o < 256; o <<= 1) {
    int y = (t >= o) ? sm[t - o] : 0;
    __syncthreads();
    sm[t] += y;
    __syncthreads();
  }
  if (i < NN) rowptr[i] = sm[t] - v;
  if (t == 255) bsum[blockIdx.x] = sm[255];
}

__global__ void scan2(int* __restrict__ bsum, int nb) {
  __shared__ int sm[256];
  int t = threadIdx.x;
  int v = (t < nb) ? bsum[t] : 0;
  sm[t] = v; __syncthreads();
  for (int o = 1; o < 256; o <<= 1) {
    int y = (t >= o) ? sm[t - o] : 0;
    __syncthreads();
    sm[t] += y;
    __syncthreads();
  }
  bsum[t] = sm[t] - v;
}

__global__ void scan3(int* __restrict__ rowptr, const int* __restrict__ bsum,
                      int* __restrict__ cursor) {
  int i = blockIdx.x * 256 + threadIdx.x;
  if (i < NN) {
    int r = rowptr[i] + bsum[blockIdx.x];
    rowptr[i] = r;
    cursor[i] = r;
  } else if (i == NN) {
    rowptr[NN] = NEDGE;
  }
}

__global__ void csr_fill(const void* __restrict__ eip, const int* __restrict__ flags,
                         int* __restrict__ cursor, int* __restrict__ adj) {
  int e = blockIdx.x * 256 + threadIdx.x;
  if (e >= NEDGE) return;
  int s, d;
  if (flags[2]) {
    s = (int)((const long long*)eip)[e];
    d = (int)((const long long*)eip)[NEDGE + e];
  } else {
    s = ((const int*)eip)[e];
    d = ((const int*)eip)[NEDGE + e];
  }
  int pos = atomicAdd(cursor + d, 1);
  adj[pos] = s;
}

// ---------- gather: one node per wave, unroll-4 edge loop ----------
template<int F, bool MASKED, bool ISBF>
__device__ __forceinline__ void gather_body(const void* __restrict__ feat,
                                            const void* __restrict__ maskp,
                                            const int* __restrict__ adj,
                                            int s0, int s1, int lane, int mu8,
                                            float* a) {
  constexpr int VEC = F / 64;
  int e = s0;
  for (; e + 4 <= s1; e += 4) {
    int n0 = adj[e], n1 = adj[e + 1], n2 = adj[e + 2], n3 = adj[e + 3];
    float m0 = 1.f, m1 = 1.f, m2 = 1.f, m3 = 1.f;
    if (MASKED) {
      m0 = maskAt(maskp, n0, mu8) ? 0.f : 1.f;
      m1 = maskAt(maskp, n1, mu8) ? 0.f : 1.f;
      m2 = maskAt(maskp, n2, mu8) ? 0.f : 1.f;
      m3 = maskAt(maskp, n3, mu8) ? 0.f : 1.f;
    }
    if (VEC == 4) {
      if (ISBF) {
        const unsigned short* fp = (const unsigned short*)feat;
        ushort4 h0 = *(const ushort4*)(fp + (size_t)n0 * F + lane * 4);
        ushort4 h1 = *(const ushort4*)(fp + (size_t)n1 * F + lane * 4);
        ushort4 h2 = *(const ushort4*)(fp + (size_t)n2 * F + lane * 4);
        ushort4 h3 = *(const ushort4*)(fp + (size_t)n3 * F + lane * 4);
        a[0] += m0 * bf2f(h0.x) + m1 * bf2f(h1.x) + m2 * bf2f(h2.x) + m3 * bf2f(h3.x);
        a[1] += m0 * bf2f(h0.y) + m1 * bf2f(h1.y) + m2 * bf2f(h2.y) + m3 * bf2f(h3.y);
        a[2] += m0 * bf2f(h0.z) + m1 * bf2f(h1.z) + m2 * bf2f(h2.z) + m3 * bf2f(h3.z);
        a[3] += m0 * bf2f(h0.w) + m1 * bf2f(h1.w) + m2 * bf2f(h2.w) + m3 * bf2f(h3.w);
      } else {
        const float* fp = (const float*)feat;
        float4 h0 = *(const float4*)(fp + (size_t)n0 * F + lane * 4);
        float4 h1 = *(const float4*)(fp + (size_t)n1 * F + lane * 4);
        float4 h2 = *(const float4*)(fp + (size_t)n2 * F + lane * 4);
        float4 h3 = *(const float4*)(fp + (size_t)n3 * F + lane * 4);
        a[0] += m0 * h0.x + m1 * h1.x + m2 * h2.x + m3 * h3.x;
        a[1] += m0 * h0.y + m1 * h1.y + m2 * h2.y + m3 * h3.y;
        a[2] += m0 * h0.z + m1 * h1.z + m2 * h2.z + m3 * h3.z;
        a[3] += m0 * h0.w + m1 * h1.w + m2 * h2.w + m3 * h3.w;
      }
    } else {
      if (ISBF) {
        const unsigned short* fp = (const unsigned short*)feat;
        ushort2 h0 = *(const ushort2*)(fp + (size_t)n0 * F + lane * 2);
        ushort2 h1 = *(const ushort2*)(fp + (size_t)n1 * F + lane * 2);
        ushort2 h2 = *(const ushort2*)(fp + (size_t)n2 * F + lane * 2);
        ushort2 h3 = *(const ushort2*)(fp + (size_t)n3 * F + lane * 2);
        a[0] += m0 * bf2f(h0.x) + m1 * bf2f(h1.x) + m2 * bf2f(h2.x) + m3 * bf2f(h3.x);
        a[1] += m0 * bf2f(h0.y) + m1 * bf2f(h1.y) + m2 * bf2f(h2.y) + m3 * bf2f(h3.y);
      } else {
        const float* fp = (const float*)feat;
        float2 h0 = *(const float2*)(fp + (size_t)n0 * F + lane * 2);
        float2 h1 = *(const float2*)(fp + (size_t)n1 * F + lane * 2);
        float2 h2 = *(const float2*)(fp + (size_t)n2 * F + lane * 2);
        float2 h3 = *(const float2*)(fp + (size_t)n3 * F + lane * 2);
        a[0] += m0 * h0.x + m1 * h1.x + m2 * h2.x + m3 * h3.x;
        a[1] += m0 * h0.y + m1 * h1.y + m2 * h2.y + m3 * h3.y;
      }
    }
  }
  for (; e < s1; ++e) {
    int s = adj[e];
    if (MASKED && maskAt(maskp, s, mu8)) continue;
    if (VEC == 4) {
      if (ISBF) {
        ushort4 h = *(const ushort4*)((const unsigned short*)feat + (size_t)s * F + lane * 4);
        a[0] += bf2f(h.x); a[1] += bf2f(h.y); a[2] += bf2f(h.z); a[3] += bf2f(h.w);
      } else {
        float4 h = *(const float4*)((const float*)feat + (size_t)s * F + lane * 4);
        a[0] += h.x; a[1] += h.y; a[2] += h.z; a[3] += h.w;
      }
    } else {
      if (ISBF) {
        ushort2 h = *(const ushort2*)((const unsigned short*)feat + (size_t)s * F + lane * 2);
        a[0] += bf2f(h.x); a[1] += bf2f(h.y);
      } else {
        float2 h = *(const float2*)((const float*)feat + (size_t)s * F + lane * 2);
        a[0] += h.x; a[1] += h.y;
      }
    }
  }
}

template<int F, bool MASKED>
__launch_bounds__(256)
__global__ void gather_k(const void* __restrict__ feat, int kind,
                         const void* __restrict__ maskp,
                         const int* __restrict__ rowptr, const int* __restrict__ adj,
                         const int* __restrict__ flags,
                         unsigned short* __restrict__ agg) {
  constexpr int VEC = F / 64;
  int v = (blockIdx.x * 256 + threadIdx.x) >> 6;
  if (v >= NN) return;
  int lane = threadIdx.x & 63;
  int fbf = (kind == K_IN) ? flags[0] : kind;
  int mu8 = flags[1];
  float a[VEC];
#pragma unroll
  for (int i = 0; i < VEC; ++i) a[i] = 0.f;
  int s0 = rowptr[v], s1 = rowptr[v + 1];
  if (fbf) gather_body<F, MASKED, true>(feat, maskp, adj, s0, s1, lane, mu8, a);
  else     gather_body<F, MASKED, false>(feat, maskp, adj, s0, s1, lane, mu8, a);
  size_t ob = (size_t)v * F + lane * VEC;
  if (VEC == 4) {
    ushort4 o; o.x = f2bf(a[0]); o.y = f2bf(a[1]); o.z = f2bf(a[2]); o.w = f2bf(a[3]);
    *(ushort4*)(agg + ob) = o;
  } else {
    ushort2 o; o.x = f2bf(a[0]); o.y = f2bf(a[1]);
    *(ushort2*)(agg + ob) = o;
  }
}

// ---------- MFMA GEMM: pipelined. 64 rows x (KO/SPLIT) cols per block.
// LDS A double-buffered (1 barrier/chunk); B fragments register double-buffered;
// A-raw global prefetch 2 chunks ahead. Pad 40 (16B-aligned rows, 2-way free).
template<int KO, int SPLIT, bool MASKF, bool AGGF, bool BNF>
__launch_bounds__(256)
__global__ void gemm_mfma(const void* __restrict__ base, int base_kind,
                          const unsigned short* __restrict__ agg,
                          const void* __restrict__ maskp,
                          const float* __restrict__ ss,      // scale[0..K), shift[K..2K)
                          const unsigned short* __restrict__ Wt,  // [KO][K] bf16
                          unsigned short* __restrict__ Cout,
                          float* __restrict__ stats,
                          const int* __restrict__ flags, int K) {
  constexpr int NTW = KO / (SPLIT * 64);          // n-tiles (of 16) per wave
  __shared__ __align__(16) unsigned short As[2][64 * 40];
  const int fbf = flags[0];
  const int mu8 = flags[1];
  const int bbf = (base_kind == K_IN) ? fbf : base_kind;
  const int tid = threadIdx.x;
  const int row0 = blockIdx.x * 64;
  const int colBase = blockIdx.y * (KO / SPLIT);
  const int srow = tid >> 2;            // 0..63
  const int sk = (tid & 3) * 8;         // 0,8,16,24
  const int grow = row0 + srow;
  const bool valid = grow < NN;
  int rmask = 0;
  if (MASKF && valid) rmask = maskAt(maskp, grow, mu8);
  const int wv = tid >> 6, lane = tid & 63;
  const int l15 = lane & 15, quad = lane >> 4;
  const int n0 = colBase + wv * (KO / SPLIT / 4);
  f32x4 zero = {0.f, 0.f, 0.f, 0.f};
  f32x4 acc[4][NTW];
#pragma unroll
  for (int m = 0; m < 4; ++m)
#pragma unroll
    for (int nt = 0; nt < NTW; ++nt) acc[m][nt] = zero;

  ushort4 pbh[2]; float4 pbf[2]; ushort4 pa[2];
  bf16x8 breg[2][NTW];

  auto issue_A = [&](int kt) {
    if (!valid) return;
    size_t gb = (size_t)grow * K + kt + sk;
    if (bbf) {
      const ushort4* P = (const ushort4*)((const unsigned short*)base + gb);
      pbh[0] = P[0]; pbh[1] = P[1];
    } else {
      const float4* P = (const float4*)((const float*)base + gb);
      pbf[0] = P[0]; pbf[1] = P[1];
    }
    if (AGGF) {
      const ushort4* Q = (const ushort4*)(agg + gb);
      pa[0] = Q[0]; pa[1] = Q[1];
    }
  };
  auto issue_B = [&](int kt, int slot) {
#pragma unroll
    for (int nt = 0; nt < NTW; ++nt)
      breg[slot][nt] = *(const bf16x8*)(Wt + (size_t)(n0 + nt * 16 + l15) * K + kt + quad * 8);
  };
  auto transform_store = [&](int kt, unsigned short* buf) {
    float v[8];
    if (valid) {
      if (bbf) {
#pragma unroll
        for (int i = 0; i < 2; ++i) {
          v[4 * i] = bf2f(pbh[i].x); v[4 * i + 1] = bf2f(pbh[i].y);
          v[4 * i + 2] = bf2f(pbh[i].z); v[4 * i + 3] = bf2f(pbh[i].w);
        }
      } else {
#pragma unroll
        for (int i = 0; i < 2; ++i) {
          v[4 * i] = pbf[i].x; v[4 * i + 1] = pbf[i].y;
          v[4 * i + 2] = pbf[i].z; v[4 * i + 3] = pbf[i].w;
        }
      }
      if (MASKF && rmask) {
#pragma unroll
        for (int i = 0; i < 8; ++i) v[i] = 0.f;
      }
      if (AGGF) {
#pragma unroll
        for (int i = 0; i < 2; ++i) {
          v[4 * i]     += bf2f(pa[i].x); v[4 * i + 1] += bf2f(pa[i].y);
          v[4 * i + 2] += bf2f(pa[i].z); v[4 * i + 3] += bf2f(pa[i].w);
        }
      }
      if (BNF) {
        int j = kt + sk;
#pragma unroll
        for (int i = 0; i < 8; ++i)
          v[i] = fmaxf(0.f, v[i] * ss[j + i] + ss[K + j + i]);
      }
    } else {
#pragma unroll
      for (int i = 0; i < 8; ++i) v[i] = 0.f;
    }
    unsigned short* dst = buf + srow * 40 + sk;
#pragma unroll
    for (int i = 0; i < 2; ++i) {
      ushort4 o;
      o.x = f2bf(v[4 * i]); o.y = f2bf(v[4 * i + 1]);
      o.z = f2bf(v[4 * i + 2]); o.w = f2bf(v[4 * i + 3]);
      *(ushort4*)(dst + 4 * i) = o;
    }
  };

  const int NC = K >> 5;
  // prologue: stage chunk 0, prefetch chunk 1 raw + chunk 0 B
  issue_A(0);
  transform_store(0, As[0]);
  issue_A(32);
  issue_B(0, 0);
  __syncthreads();

  for (int i = 0; i < NC; ++i) {
    int kt = i << 5;
    if (i + 1 < NC) transform_store(kt + 32, As[(i + 1) & 1]);  // uses raw_{i+1}
    if (i + 2 < NC) issue_A(kt + 64);                           // raw_{i+2} in flight
    if (i + 1 < NC) issue_B(kt + 32, (i + 1) & 1);              // B_{i+1} in flight
    bf16x8 afr[4];
#pragma unroll
    for (int m = 0; m < 4; ++m)
      afr[m] = *(const bf16x8*)(As[i & 1] + (m * 16 + l15) * 40 + quad * 8);
#pragma unroll
    for (int nt = 0; nt < NTW; ++nt)
#pragma unroll
      for (int m = 0; m < 4; ++m)
        acc[m][nt] = __builtin_amdgcn_mfma_f32_16x16x32_bf16(afr[m], breg[i & 1][nt], acc[m][nt], 0, 0, 0);
    __syncthreads();
  }

#pragma unroll
  for (int m = 0; m < 4; ++m)
#pragma unroll
    for (int r = 0; r < 4; ++r) {
      int gr = row0 + m * 16 + quad * 4 + r;
      if (gr < NN) {
        size_t ob = (size_t)gr * KO + n0 + l15;
#pragma unroll
        for (int nt = 0; nt < NTW; ++nt)
          Cout[ob + nt * 16] = f2bf(acc[m][nt][r]);
      }
    }

#pragma unroll
  for (int nt = 0; nt < NTW; ++nt) {
    float s = 0.f, q = 0.f;
#pragma unroll
    for (int m = 0; m < 4; ++m)
#pragma unroll
      for (int r = 0; r < 4; ++r) {
        float vv = acc[m][nt][r];          // invalid rows are 0 (A zeroed)
        s += vv; q += vv * vv;
      }
    s += __shfl_xor(s, 16); s += __shfl_xor(s, 32);
    q += __shfl_xor(q, 16); q += __shfl_xor(q, 32);
    if (quad == 0) {
      int col = n0 + nt * 16 + l15;
      atomicAdd(stats + col, s);
      atomicAdd(stats + KO + col, q);
    }
  }
}

// ---------- BN finalize ----------
__global__ void bn_finalize(const float* __restrict__ sums, const void* __restrict__ g,
                            const void* __restrict__ b, const int* __restrict__ flags,
                            float* __restrict__ ss, int Ko) {
  int c = blockIdx.x * blockDim.x + threadIdx.x;
  if (c < Ko) {
    const float invN = 1.f / (float)NN;
    float mu = sums[c] * invN;
    float var = sums[Ko + c] * invN - mu * mu;
    float sc = load1f(g, c, flags[0]) * rsqrtf(var + 1e-5f);
    ss[c] = sc;
    ss[Ko + c] = load1f(b, c, flags[0]) - mu * sc;
  }
}

// ---------- relu(bn(u)) -> bf16 X, optional row mask-zeroing; u is bf16 ----------
template<bool MASKED>
__launch_bounds__(256)
__global__ void bnrelu_ew(const unsigned short* __restrict__ in, const float* __restrict__ ss,
                          const void* __restrict__ maskp, const int* __restrict__ flags,
                          unsigned short* __restrict__ out, int Ko) {
  int idx = blockIdx.x * 256 + threadIdx.x;
  int total = NN * (Ko / 4);
  if (idx >= total) return;
  int row = idx / (Ko / 4);
  int j = (idx % (Ko / 4)) * 4;
  ushort4 h = *(const ushort4*)(in + (size_t)idx * 4);
  float4 o;
  o.x = fmaxf(0.f, bf2f(h.x) * ss[j]     + ss[Ko + j]);
  o.y = fmaxf(0.f, bf2f(h.y) * ss[j + 1] + ss[Ko + j + 1]);
  o.z = fmaxf(0.f, bf2f(h.z) * ss[j + 2] + ss[Ko + j + 2]);
  o.w = fmaxf(0.f, bf2f(h.w) * ss[j + 3] + ss[Ko + j + 3]);
  if (MASKED && maskAt(maskp, row, flags[1])) o = make_float4(0.f, 0.f, 0.f, 0.f);
  ushort4 b4; b4.x = f2bf(o.x); b4.y = f2bf(o.y); b4.z = f2bf(o.z); b4.w = f2bf(o.w);
  *(ushort4*)(out + (size_t)idx * 4) = b4;
}

// ---------- recon loss: one row per wave, channel-spread binned atomics ----------
// accb layout: sum at accb[bin*16], cnt at accb[1024 + bin*16]
__launch_bounds__(256)
__global__ void loss_kernel(const unsigned short* __restrict__ u2, const float* __restrict__ ss,
                            const void* __restrict__ xp, const void* __restrict__ maskp,
                            const int* __restrict__ flags,
                            unsigned short* __restrict__ rx, float* __restrict__ accb) {
  __shared__ float redS[4], redC[4];
  int r = (blockIdx.x * 256 + threadIdx.x) >> 6;
  int lane = threadIdx.x & 63;
  int wv = threadIdx.x >> 6;
  int fbf = flags[0], mu8 = flags[1];
  float lsum = 0.f, lcnt = 0.f;
  if (r < NN) {
    size_t b0 = (size_t)r * 128;
    int c0 = 2 * lane, c1 = 2 * lane + 1;
    ushort2 uh = *(const ushort2*)(u2 + b0 + c0);
    float a0 = fmaxf(0.f, bf2f(uh.x) * ss[c0] + ss[128 + c0]);
    float a1 = fmaxf(0.f, bf2f(uh.y) * ss[c1] + ss[128 + c1]);
    float x0, x1;
    if (fbf) {
      ushort2 xh = *(const ushort2*)((const unsigned short*)xp + b0 + c0);
      x0 = bf2f(xh.x); x1 = bf2f(xh.y);
    } else {
      float2 xf = *(const float2*)((const float*)xp + b0 + c0);
      x0 = xf.x; x1 = xf.y;
    }
    ushort2 o; o.x = f2bf(a0); o.y = f2bf(a1);
    *(ushort2*)(rx + b0 + c0) = o;
    float dot = a0 * x0 + a1 * x1;
    float na = a0 * a0 + a1 * a1;
    float nx = x0 * x0 + x1 * x1;
#pragma unroll
    for (int off = 32; off > 0; off >>= 1) {
      dot += __shfl_xor(dot, off);
      na  += __shfl_xor(na, off);
      nx  += __shfl_xor(nx, off);
    }
    float cs = dot / (fmaxf(sqrtf(na), 1e-12f) * fmaxf(sqrtf(nx), 1e-12f));
    if (maskAt(maskp, r, mu8)) { lsum = 1.f - cs; lcnt = 1.f; }
  }
  if (lane == 0) { redS[wv] = lsum; redC[wv] = lcnt; }
  __syncthreads();
  if (threadIdx.x == 0) {
    float s = redS[0] + redS[1] + redS[2] + redS[3];
    float c = redC[0] + redC[1] + redC[2] + redC[3];
    int bin = (blockIdx.x & 63) * 16;
    atomicAdd(&accb[bin], s);
    atomicAdd(&accb[1024 + bin], c);
  }
}

// ---------- contrastive: one row per wave, channel-spread binned atomics ----------
__launch_bounds__(256)
__global__ void cl_kernel(const unsigned short* __restrict__ r1,
                          const unsigned short* __restrict__ r2,
                          float* __restrict__ accb) {
  __shared__ float redS[4];
  int r = (blockIdx.x * 256 + threadIdx.x) >> 6;
  int lane = threadIdx.x & 63;
  int wv = threadIdx.x >> 6;
  float lsum = 0.f;
  if (r < NN) {
    size_t b0 = (size_t)r * 128;
    int c0 = 2 * lane;
    ushort2 h1 = *(const ushort2*)(r1 + b0 + c0);
    ushort2 h2 = *(const ushort2*)(r2 + b0 + c0);
    float a0 = bf2f(h1.x), a1 = bf2f(h1.y);
    float c0v = bf2f(h2.x), c1v = bf2f(h2.y);
    float dot = a0 * c0v + a1 * c1v;
    float na = a0 * a0 + a1 * a1;
    float nb = c0v * c0v + c1v * c1v;
#pragma unroll
    for (int off = 32; off > 0; off >>= 1) {
      dot += __shfl_xor(dot, off);
      na  += __shfl_xor(na, off);
      nb  += __shfl_xor(nb, off);
    }
    float cs = dot / (fmaxf(sqrtf(na), 1e-12f) * fmaxf(sqrtf(nb), 1e-12f));
    lsum = 1.f - cs;
  }
  if (lane == 0) redS[wv] = lsum;
  __syncthreads();
  if (threadIdx.x == 0) {
    float s = redS[0] + redS[1] + redS[2] + redS[3];
    atomicAdd(&accb[(blockIdx.x & 63) * 16], s);
  }
}

// ---------- final: reduce 64-bin accumulators (stride-16) ----------
// groups: 0=l1sum, 1024=l1cnt, 2048=l2sum, 3072=l2cnt, 4096=cl
__global__ void final_kernel(const float* __restrict__ acc, void* __restrict__ out,
                             const int* __restrict__ flags) {
  int lane = threadIdx.x & 63;
  float v0 = acc[lane * 16], v1 = acc[1024 + lane * 16], v2 = acc[2048 + lane * 16];
  float v3 = acc[3072 + lane * 16], v4 = acc[4096 + lane * 16];
#pragma unroll
  for (int off = 32; off > 0; off >>= 1) {
    v0 += __shfl_xor(v0, off);
    v1 += __shfl_xor(v1, off);
    v2 += __shfl_xor(v2, off);
    v3 += __shfl_xor(v3, off);
    v4 += __shfl_xor(v4, off);
  }
  if (threadIdx.x == 0 && blockIdx.x == 0) {
    float v = v0 / v1 + v2 / v3 + 0.1f * (v4 / (float)NN);
    if (flags[0]) ((unsigned short*)out)[0] = f2bf(v);
    else          ((float*)out)[0] = v;
  }
}

extern "C" void kernel_launch(void* const* d_in, const int* in_sizes, int n_in,
                              void* d_out, int out_size, void* d_ws, size_t ws_size,
                              hipStream_t stream) {
  const void* x   = d_in[0];
  const void* ei1 = d_in[1];
  const void* ei2 = d_in[2];
  const void* m1  = d_in[3];
  const void* m2  = d_in[4];
  const void* e0_w1 = d_in[6],  *e0_w2 = d_in[7],  *e0_bg = d_in[8],  *e0_bb = d_in[9];
  const void* e0_ng = d_in[10], *e0_nb = d_in[11];
  const void* e1_w1 = d_in[12], *e1_w2 = d_in[13], *e1_bg = d_in[14], *e1_bb = d_in[15];
  const void* e1_ng = d_in[16], *e1_nb = d_in[17];
  const void* dw1 = d_in[18], *dw2 = d_in[19], *dbg = d_in[20], *dbb = d_in[21];
  const void* dng = d_in[22], *dnb = d_in[23];

  // ---- workspace layout ----
  char* p = (char*)d_ws;
  const size_t OFS_T      = 0;                                    // bf16 N*512
  const size_t OFS_AGG    = OFS_T      + (size_t)NN * 512 * 2;    // bf16 N*256 (aliased as u)
  const size_t OFS_X      = OFS_AGG    + (size_t)NN * 256 * 2;    // bf16 N*256
  const size_t OFS_RX1    = OFS_X      + (size_t)NN * 256 * 2;    // bf16 N*128
  const size_t OFS_RX2    = OFS_RX1    + (size_t)NN * 128 * 2;
  const size_t OFS_WT     = OFS_RX2    + (size_t)NN * 128 * 2;    // bf16 655360
  const size_t OFS_ROWPTR = OFS_WT     + 655360 * 2;              // int 50016
  const size_t OFS_CURSOR = OFS_ROWPTR + 50016 * 4;               // int 50016
  const size_t OFS_ADJ    = OFS_CURSOR + 50016 * 4;               // int NEDGE
  const size_t OFS_BSUM   = OFS_ADJ    + (size_t)NEDGE * 4;       // int 256
  const size_t OFS_STATS  = OFS_BSUM   + 256 * 4;                 // f 1024
  const size_t OFS_SS     = OFS_STATS  + 1024 * 4;                // f 1024
  const size_t OFS_ACC    = OFS_SS     + 1024 * 4;                // f 5120 (binned, stride16)
  const size_t OFS_FLAGS  = OFS_ACC    + 5120 * 4;                // i 4
  const size_t NEED       = OFS_FLAGS + 16;

  if (ws_size < NEED) {
    diag_kernel<<<1, 64, 0, stream>>>(d_out, (float)(ws_size >> 20));
    return;
  }

  unsigned short* T   = (unsigned short*)(p + OFS_T);
  unsigned short* AGG = (unsigned short*)(p + OFS_AGG);
  unsigned short* U   = AGG;   // alias: agg dead once g2 writes u
  unsigned short* X   = (unsigned short*)(p + OFS_X);
  unsigned short* RX1 = (unsigned short*)(p + OFS_RX1);
  unsigned short* RX2 = (unsigned short*)(p + OFS_RX2);
  unsigned short* WT  = (unsigned short*)(p + OFS_WT);
  int* rowptr = (int*)(p + OFS_ROWPTR);
  int* cursor = (int*)(p + OFS_CURSOR);
  int* adj    = (int*)(p + OFS_ADJ);
  int* bsum   = (int*)(p + OFS_BSUM);
  float* stats = (float*)(p + OFS_STATS);
  float* ss    = (float*)(p + OFS_SS);
  float* acc   = (float*)(p + OFS_ACC);
  int*   flags = (int*)(p + OFS_FLAGS);

  const int EB = (NEDGE + 255) / 256;        // 1250
  const int SB = (NN + 255) / 256;           // 196
  const int GB = (NN + 63) / 64;             // 782 row-blocks
  const int WB = (NN + 3) / 4;               // 12500 blocks (1 node/wave)
  const dim3 gS2(GB, 2), gS1(GB, 1);

  hipMemsetAsync(acc, 0, 5120 * sizeof(float) + 4 * sizeof(int), stream);
  sniff_kernel<<<1, 64, 0, stream>>>(e0_bg, m1, ei1, flags);

  // weight transposes (once; bf16)
  transpose_w<<<(128 * 512 + 255) / 256, 256, 0, stream>>>(e0_w1, flags, WT + 0,      128, 512);
  transpose_w<<<(512 * 256 + 255) / 256, 256, 0, stream>>>(e0_w2, flags, WT + 65536,  512, 256);
  transpose_w<<<(256 * 512 + 255) / 256, 256, 0, stream>>>(e1_w1, flags, WT + 196608, 256, 512);
  transpose_w<<<(512 * 256 + 255) / 256, 256, 0, stream>>>(e1_w2, flags, WT + 327680, 512, 256);
  transpose_w<<<(256 * 512 + 255) / 256, 256, 0, stream>>>(dw1,   flags, WT + 458752, 256, 512);
  transpose_w<<<(512 * 128 + 255) / 256, 256, 0, stream>>>(dw2,   flags, WT + 589824, 512, 128);

  for (int pass = 0; pass < 2; ++pass) {
    const void* ei = pass ? ei2 : ei1;
    const void* mk = pass ? m2 : m1;
    unsigned short* rx = pass ? RX2 : RX1;
    float* accp = acc + 2048 * pass;

    // ---- CSR build ----
    hipMemsetAsync(cursor, 0, 50016 * 4, stream);
    csr_hist<<<EB, 256, 0, stream>>>(ei, flags, cursor);
    scan1<<<SB, 256, 0, stream>>>(cursor, rowptr, bsum);
    scan2<<<1, 256, 0, stream>>>(bsum, SB);
    scan3<<<SB, 256, 0, stream>>>(rowptr, bsum, cursor);
    csr_fill<<<EB, 256, 0, stream>>>(ei, flags, cursor, adj);

    // ---- encoder L0 (128 -> 512 -> 256) ----
    gather_k<128, true><<<WB, 256, 0, stream>>>(x, K_IN, mk, rowptr, adj, flags, AGG);
    hipMemsetAsync(stats, 0, 1024 * 4, stream);
    gemm_mfma<512, 2, true, true, false><<<gS2, 256, 0, stream>>>(
        x, K_IN, AGG, mk, nullptr, WT + 0, T, stats, flags, 128);
    bn_finalize<<<2, 256, 0, stream>>>(stats, e0_bg, e0_bb, flags, ss, 512);
    hipMemsetAsync(stats, 0, 512 * 4, stream);
    gemm_mfma<256, 2, false, false, true><<<gS2, 256, 0, stream>>>(
        T, K_BF16, nullptr, nullptr, ss, WT + 65536, U, stats, flags, 512);
    bn_finalize<<<1, 256, 0, stream>>>(stats, e0_ng, e0_nb, flags, ss, 256);
    bnrelu_ew<false><<<12500, 256, 0, stream>>>(U, ss, nullptr, flags, X, 256);

    // ---- encoder L1 (256 -> 512 -> 256) ----
    gather_k<256, false><<<WB, 256, 0, stream>>>(X, K_BF16, nullptr, rowptr, adj, flags, AGG);
    hipMemsetAsync(stats, 0, 1024 * 4, stream);
    gemm_mfma<512, 2, false, true, false><<<gS2, 256, 0, stream>>>(
        X, K_BF16, AGG, nullptr, nullptr, WT + 196608, T, stats, flags, 256);
    bn_finalize<<<2, 256, 0, stream>>>(stats, e1_bg, e1_bb, flags, ss, 512);
    hipMemsetAsync(stats, 0, 512 * 4, stream);
    gemm_mfma<256, 2, false, false, true><<<gS2, 256, 0, stream>>>(
        T, K_BF16, nullptr, nullptr, ss, WT + 327680, U, stats, flags, 512);
    bn_finalize<<<1, 256, 0, stream>>>(stats, e1_ng, e1_nb, flags, ss, 256);
    bnrelu_ew<true><<<12500, 256, 0, stream>>>(U, ss, mk, flags, X, 256);   // re_h (masked)

    // ---- decoder (256 -> 512 -> 128) ----
    gather_k<256, false><<<WB, 256, 0, stream>>>(X, K_BF16, nullptr, rowptr, adj, flags, AGG);
    hipMemsetAsync(stats, 0, 1024 * 4, stream);
    gemm_mfma<512, 2, false, true, false><<<gS2, 256, 0, stream>>>(
        X, K_BF16, AGG, nullptr, nullptr, WT + 458752, T, stats, flags, 256);
    bn_finalize<<<2, 256, 0, stream>>>(stats, dbg, dbb, flags, ss, 512);
    hipMemsetAsync(stats, 0, 256 * 4, stream);
    gemm_mfma<128, 1, false, false, true><<<gS1, 256, 0, stream>>>(
        T, K_BF16, nullptr, nullptr, ss, WT + 589824, U, stats, flags, 512);
    bn_finalize<<<1, 256, 0, stream>>>(stats, dng, dnb, flags, ss, 128);

    loss_kernel<<<WB, 256, 0, stream>>>(U, ss, x, mk, flags, rx, accp);
  }

  cl_kernel<<<WB, 256, 0, stream>>>(RX1, RX2, acc + 4096);
  final_kernel<<<1, 64, 0, stream>>>(acc, d_out, flags);
}

// Round 9
// 1297.757 us; speedup vs baseline: 7.0580x; 7.0580x over previous
//
#include <hip/hip_runtime.h>
#include <hip/hip_bf16.h>
#include <cstdint>

#define NN 50000
#define NEDGE 320000

#define K_F32 0
#define K_BF16 1
#define K_IN 2   // resolve via flags[0]

typedef __attribute__((ext_vector_type(8))) short bf16x8;
typedef __attribute__((ext_vector_type(4))) float f32x4;

// ---------- helpers ----------
__device__ __forceinline__ float bf2f(unsigned short u) {
  return __uint_as_float(((unsigned)u) << 16);
}
__device__ __forceinline__ unsigned short f2bf(float f) {
  unsigned u = __float_as_uint(f);
  unsigned r = ((u >> 16) & 1u) + 0x7FFFu;   // RNE
  return (unsigned short)((u + r) >> 16);
}
__device__ __forceinline__ float load1f(const void* p, size_t i, int isbf) {
  return isbf ? bf2f(((const unsigned short*)p)[i]) : ((const float*)p)[i];
}
__device__ __forceinline__ int maskAt(const void* m, int i, int u8) {
  return u8 ? (int)((const unsigned char*)m)[i] : ((const int*)m)[i];
}

// ---------- sniff dtypes (flags[0]=floats bf16, [1]=masks u8, [2]=edges i64) ----------
__global__ void sniff_kernel(const void* bg, const void* mask, const void* ei, int* flags) {
  if (threadIdx.x == 0 && blockIdx.x == 0) {
    unsigned w = *(const unsigned*)bg;
    flags[0] = (w == 0x3F800000u) ? 0 : 1;
    const unsigned char* mb = (const unsigned char*)mask;
    int u8 = 0;
    for (int i = 0; i < 1024; ++i)
      if ((i & 3) && mb[i]) { u8 = 1; break; }
    flags[1] = u8;
    const int* ew = (const int*)ei;
    int i64 = 1;
    for (int i = 0; i < 256; ++i)
      if (ew[2 * i + 1] != 0) { i64 = 0; break; }
    flags[2] = i64;
  }
}

__global__ void diag_kernel(void* out, float v) {
  if (threadIdx.x == 0 && blockIdx.x == 0) ((unsigned short*)out)[0] = f2bf(v);
}

// ---------- weight transpose: Wt[n][k] = bf16(W[k][n]) ----------
__global__ void transpose_w(const void* __restrict__ W, const int* __restrict__ flags,
                            unsigned short* __restrict__ Wt, int K, int Ko) {
  int idx = blockIdx.x * 256 + threadIdx.x;
  if (idx >= K * Ko) return;
  int n = idx / K, k = idx - n * K;
  Wt[idx] = f2bf(load1f(W, (size_t)k * Ko + n, flags[0]));
}

// ---------- CSR build ----------
__global__ void csr_hist(const void* __restrict__ eip, const int* __restrict__ flags,
                         int* __restrict__ deg) {
  int e = blockIdx.x * 256 + threadIdx.x;
  if (e >= NEDGE) return;
  int d = flags[2] ? (int)((const long long*)eip)[NEDGE + e] : ((const int*)eip)[NEDGE + e];
  atomicAdd(deg + d, 1);
}

__global__ void scan1(const int* __restrict__ deg, int* __restrict__ rowptr,
                      int* __restrict__ bsum) {
  __shared__ int sm[256];
  int t = threadIdx.x, i = blockIdx.x * 256 + t;
  int v = (i < NN) ? deg[i] : 0;
  sm[t] = v; __syncthreads();
  for (int o = 1; o < 256; o <<= 1) {
    int y = (t >= o) ? sm[t - o] : 0;
    __syncthreads();
    sm[t] += y;
    __syncthreads();
  }
  if (i < NN) rowptr[i] = sm[t] - v;
  if (t == 255) bsum[blockIdx.x] = sm[255];
}

__global__ void scan2(int* __restrict__ bsum, int nb) {
  __shared__ int sm[256];
  int t = threadIdx.x;
  int v = (t < nb) ? bsum[t] : 0;
  sm[t] = v; __syncthreads();
  for (int o = 1; o < 256; o <<= 1) {
    int y = (t >= o) ? sm[t - o] : 0;
    __syncthreads();
    sm[t] += y;
    __syncthreads();
  }
  bsum[t] = sm[t] - v;
}

__global__ void scan3(int* __restrict__ rowptr, const int* __restrict__ bsum,
                      int* __restrict__ cursor) {
  int i = blockIdx.x * 256 + threadIdx.x;
  if (i < NN) {
    int r = rowptr[i] + bsum[blockIdx.x];
    rowptr[i] = r;
    cursor[i] = r;
  } else if (i == NN) {
    rowptr[NN] = NEDGE;
  }
}

__global__ void csr_fill(const void* __restrict__ eip, const int* __restrict__ flags,
                         int* __restrict__ cursor, int* __restrict__ adj) {
  int e = blockIdx.x * 256 + threadIdx.x;
  if (e >= NEDGE) return;
  int s, d;
  if (flags[2]) {
    s = (int)((const long long*)eip)[e];
    d = (int)((const long long*)eip)[NEDGE + e];
  } else {
    s = ((const int*)eip)[e];
    d = ((const int*)eip)[NEDGE + e];
  }
  int pos = atomicAdd(cursor + d, 1);
  adj[pos] = s;
}

// ---------- gather: one node per wave, unroll-4 edge loop ----------
template<int F, bool MASKED, bool ISBF>
__device__ __forceinline__ void gather_body(const void* __restrict__ feat,
                                            const void* __restrict__ maskp,
                                            const int* __restrict__ adj,
                                            int s0, int s1, int lane, int mu8,
                                            float* a) {
  constexpr int VEC = F / 64;
  int e = s0;
  for (; e + 4 <= s1; e += 4) {
    int n0 = adj[e], n1 = adj[e + 1], n2 = adj[e + 2], n3 = adj[e + 3];
    float m0 = 1.f, m1 = 1.f, m2 = 1.f, m3 = 1.f;
    if (MASKED) {
      m0 = maskAt(maskp, n0, mu8) ? 0.f : 1.f;
      m1 = maskAt(maskp, n1, mu8) ? 0.f : 1.f;
      m2 = maskAt(maskp, n2, mu8) ? 0.f : 1.f;
      m3 = maskAt(maskp, n3, mu8) ? 0.f : 1.f;
    }
    if (VEC == 4) {
      if (ISBF) {
        const unsigned short* fp = (const unsigned short*)feat;
        ushort4 h0 = *(const ushort4*)(fp + (size_t)n0 * F + lane * 4);
        ushort4 h1 = *(const ushort4*)(fp + (size_t)n1 * F + lane * 4);
        ushort4 h2 = *(const ushort4*)(fp + (size_t)n2 * F + lane * 4);
        ushort4 h3 = *(const ushort4*)(fp + (size_t)n3 * F + lane * 4);
        a[0] += m0 * bf2f(h0.x) + m1 * bf2f(h1.x) + m2 * bf2f(h2.x) + m3 * bf2f(h3.x);
        a[1] += m0 * bf2f(h0.y) + m1 * bf2f(h1.y) + m2 * bf2f(h2.y) + m3 * bf2f(h3.y);
        a[2] += m0 * bf2f(h0.z) + m1 * bf2f(h1.z) + m2 * bf2f(h2.z) + m3 * bf2f(h3.z);
        a[3] += m0 * bf2f(h0.w) + m1 * bf2f(h1.w) + m2 * bf2f(h2.w) + m3 * bf2f(h3.w);
      } else {
        const float* fp = (const float*)feat;
        float4 h0 = *(const float4*)(fp + (size_t)n0 * F + lane * 4);
        float4 h1 = *(const float4*)(fp + (size_t)n1 * F + lane * 4);
        float4 h2 = *(const float4*)(fp + (size_t)n2 * F + lane * 4);
        float4 h3 = *(const float4*)(fp + (size_t)n3 * F + lane * 4);
        a[0] += m0 * h0.x + m1 * h1.x + m2 * h2.x + m3 * h3.x;
        a[1] += m0 * h0.y + m1 * h1.y + m2 * h2.y + m3 * h3.y;
        a[2] += m0 * h0.z + m1 * h1.z + m2 * h2.z + m3 * h3.z;
        a[3] += m0 * h0.w + m1 * h1.w + m2 * h2.w + m3 * h3.w;
      }
    } else {
      if (ISBF) {
        const unsigned short* fp = (const unsigned short*)feat;
        ushort2 h0 = *(const ushort2*)(fp + (size_t)n0 * F + lane * 2);
        ushort2 h1 = *(const ushort2*)(fp + (size_t)n1 * F + lane * 2);
        ushort2 h2 = *(const ushort2*)(fp + (size_t)n2 * F + lane * 2);
        ushort2 h3 = *(const ushort2*)(fp + (size_t)n3 * F + lane * 2);
        a[0] += m0 * bf2f(h0.x) + m1 * bf2f(h1.x) + m2 * bf2f(h2.x) + m3 * bf2f(h3.x);
        a[1] += m0 * bf2f(h0.y) + m1 * bf2f(h1.y) + m2 * bf2f(h2.y) + m3 * bf2f(h3.y);
      } else {
        const float* fp = (const float*)feat;
        float2 h0 = *(const float2*)(fp + (size_t)n0 * F + lane * 2);
        float2 h1 = *(const float2*)(fp + (size_t)n1 * F + lane * 2);
        float2 h2 = *(const float2*)(fp + (size_t)n2 * F + lane * 2);
        float2 h3 = *(const float2*)(fp + (size_t)n3 * F + lane * 2);
        a[0] += m0 * h0.x + m1 * h1.x + m2 * h2.x + m3 * h3.x;
        a[1] += m0 * h0.y + m1 * h1.y + m2 * h2.y + m3 * h3.y;
      }
    }
  }
  for (; e < s1; ++e) {
    int s = adj[e];
    if (MASKED && maskAt(maskp, s, mu8)) continue;
    if (VEC == 4) {
      if (ISBF) {
        ushort4 h = *(const ushort4*)((const unsigned short*)feat + (size_t)s * F + lane * 4);
        a[0] += bf2f(h.x); a[1] += bf2f(h.y); a[2] += bf2f(h.z); a[3] += bf2f(h.w);
      } else {
        float4 h = *(const float4*)((const float*)feat + (size_t)s * F + lane * 4);
        a[0] += h.x; a[1] += h.y; a[2] += h.z; a[3] += h.w;
      }
    } else {
      if (ISBF) {
        ushort2 h = *(const ushort2*)((const unsigned short*)feat + (size_t)s * F + lane * 2);
        a[0] += bf2f(h.x); a[1] += bf2f(h.y);
      } else {
        float2 h = *(const float2*)((const float*)feat + (size_t)s * F + lane * 2);
        a[0] += h.x; a[1] += h.y;
      }
    }
  }
}

template<int F, bool MASKED>
__launch_bounds__(256)
__global__ void gather_k(const void* __restrict__ feat, int kind,
                         const void* __restrict__ maskp,
                         const int* __restrict__ rowptr, const int* __restrict__ adj,
                         const int* __restrict__ flags,
                         unsigned short* __restrict__ agg) {
  constexpr int VEC = F / 64;
  int v = (blockIdx.x * 256 + threadIdx.x) >> 6;
  if (v >= NN) return;
  int lane = threadIdx.x & 63;
  int fbf = (kind == K_IN) ? flags[0] : kind;
  int mu8 = flags[1];
  float a[VEC];
#pragma unroll
  for (int i = 0; i < VEC; ++i) a[i] = 0.f;
  int s0 = rowptr[v], s1 = rowptr[v + 1];
  if (fbf) gather_body<F, MASKED, true>(feat, maskp, adj, s0, s1, lane, mu8, a);
  else     gather_body<F, MASKED, false>(feat, maskp, adj, s0, s1, lane, mu8, a);
  size_t ob = (size_t)v * F + lane * VEC;
  if (VEC == 4) {
    ushort4 o; o.x = f2bf(a[0]); o.y = f2bf(a[1]); o.z = f2bf(a[2]); o.w = f2bf(a[3]);
    *(ushort4*)(agg + ob) = o;
  } else {
    ushort2 o; o.x = f2bf(a[0]); o.y = f2bf(a[1]);
    *(ushort2*)(agg + ob) = o;
  }
}

// ---------- MFMA GEMM: fully-unrolled pipelined K-loop (K compile-time).
// 64 rows x (KO/SPLIT) cols per block. LDS A double-buffered, pad 40 (16B rows);
// B fragments register double-buffered with compile-time buffer indices.
template<int K, int KO, int SPLIT, bool MASKF, bool AGGF, bool BNF>
__launch_bounds__(256)
__global__ void gemm_mfma(const void* __restrict__ base, int base_kind,
                          const unsigned short* __restrict__ agg,
                          const void* __restrict__ maskp,
                          const float* __restrict__ ss,      // scale[0..K), shift[K..2K)
                          const unsigned short* __restrict__ Wt,  // [KO][K] bf16
                          unsigned short* __restrict__ Cout,
                          float* __restrict__ stats,
                          const int* __restrict__ flags) {
  constexpr int NTW = KO / (SPLIT * 64);          // n-tiles (of 16) per wave
  constexpr int NC = K / 32;                      // K-chunks
  __shared__ __align__(16) unsigned short As[2][64 * 40];
  const int fbf = flags[0];
  const int mu8 = flags[1];
  const int bbf = (base_kind == K_IN) ? fbf : base_kind;
  const int tid = threadIdx.x;
  const int row0 = blockIdx.x * 64;
  const int colBase = blockIdx.y * (KO / SPLIT);
  const int srow = tid >> 2;            // 0..63
  const int sk = (tid & 3) * 8;         // 0,8,16,24
  const int grow = row0 + srow;
  const bool valid = grow < NN;
  int rmask = 0;
  if (MASKF && valid) rmask = maskAt(maskp, grow, mu8);
  const int wv = tid >> 6, lane = tid & 63;
  const int l15 = lane & 15, quad = lane >> 4;
  const int n0 = colBase + wv * (KO / SPLIT / 4);
  f32x4 zero = {0.f, 0.f, 0.f, 0.f};
  f32x4 acc[4][NTW];
#pragma unroll
  for (int m = 0; m < 4; ++m)
#pragma unroll
    for (int nt = 0; nt < NTW; ++nt) acc[m][nt] = zero;

  ushort4 pbh[2]; float4 pbf[2]; ushort4 pa[2];
  bf16x8 breg[2][NTW];

  auto issue_A = [&](int kt) {
    if (!valid) return;
    size_t gb = (size_t)grow * K + kt + sk;
    if (bbf) {
      const ushort4* P = (const ushort4*)((const unsigned short*)base + gb);
      pbh[0] = P[0]; pbh[1] = P[1];
    } else {
      const float4* P = (const float4*)((const float*)base + gb);
      pbf[0] = P[0]; pbf[1] = P[1];
    }
    if (AGGF) {
      const ushort4* Q = (const ushort4*)(agg + gb);
      pa[0] = Q[0]; pa[1] = Q[1];
    }
  };
  auto transform_store = [&](int kt, unsigned short* buf) {
    float v[8];
    if (valid) {
      if (bbf) {
#pragma unroll
        for (int i = 0; i < 2; ++i) {
          v[4 * i] = bf2f(pbh[i].x); v[4 * i + 1] = bf2f(pbh[i].y);
          v[4 * i + 2] = bf2f(pbh[i].z); v[4 * i + 3] = bf2f(pbh[i].w);
        }
      } else {
#pragma unroll
        for (int i = 0; i < 2; ++i) {
          v[4 * i] = pbf[i].x; v[4 * i + 1] = pbf[i].y;
          v[4 * i + 2] = pbf[i].z; v[4 * i + 3] = pbf[i].w;
        }
      }
      if (MASKF && rmask) {
#pragma unroll
        for (int i = 0; i < 8; ++i) v[i] = 0.f;
      }
      if (AGGF) {
#pragma unroll
        for (int i = 0; i < 2; ++i) {
          v[4 * i]     += bf2f(pa[i].x); v[4 * i + 1] += bf2f(pa[i].y);
          v[4 * i + 2] += bf2f(pa[i].z); v[4 * i + 3] += bf2f(pa[i].w);
        }
      }
      if (BNF) {
        int j = kt + sk;
#pragma unroll
        for (int i = 0; i < 8; ++i)
          v[i] = fmaxf(0.f, v[i] * ss[j + i] + ss[K + j + i]);
      }
    } else {
#pragma unroll
      for (int i = 0; i < 8; ++i) v[i] = 0.f;
    }
    unsigned short* dst = buf + srow * 40 + sk;
#pragma unroll
    for (int i = 0; i < 2; ++i) {
      ushort4 o;
      o.x = f2bf(v[4 * i]); o.y = f2bf(v[4 * i + 1]);
      o.z = f2bf(v[4 * i + 2]); o.w = f2bf(v[4 * i + 3]);
      *(ushort4*)(dst + 4 * i) = o;
    }
  };

  // prologue: stage chunk 0, prefetch chunk 1 raw + chunk 0 B
  issue_A(0);
  transform_store(0, As[0]);
  if (NC > 1) issue_A(32);
#pragma unroll
  for (int nt = 0; nt < NTW; ++nt)
    breg[0][nt] = *(const bf16x8*)(Wt + (size_t)(n0 + nt * 16 + l15) * K + quad * 8);
  __syncthreads();

#pragma unroll
  for (int i = 0; i < NC; ++i) {
    constexpr_helper:;
    const int kt = i << 5;
    if (i + 1 < NC) transform_store(kt + 32, As[(i + 1) & 1]);  // consumes raw_{i+1}
    if (i + 2 < NC) issue_A(kt + 64);                           // raw_{i+2} in flight
    if (i + 1 < NC) {
#pragma unroll
      for (int nt = 0; nt < NTW; ++nt)
        breg[(i + 1) & 1][nt] =
            *(const bf16x8*)(Wt + (size_t)(n0 + nt * 16 + l15) * K + kt + 32 + quad * 8);
    }
    bf16x8 afr[4];
#pragma unroll
    for (int m = 0; m < 4; ++m)
      afr[m] = *(const bf16x8*)(As[i & 1] + (m * 16 + l15) * 40 + quad * 8);
#pragma unroll
    for (int nt = 0; nt < NTW; ++nt)
#pragma unroll
      for (int m = 0; m < 4; ++m)
        acc[m][nt] = __builtin_amdgcn_mfma_f32_16x16x32_bf16(afr[m], breg[i & 1][nt], acc[m][nt], 0, 0, 0);
    __syncthreads();
  }

#pragma unroll
  for (int m = 0; m < 4; ++m)
#pragma unroll
    for (int r = 0; r < 4; ++r) {
      int gr = row0 + m * 16 + quad * 4 + r;
      if (gr < NN) {
        size_t ob = (size_t)gr * KO + n0 + l15;
#pragma unroll
        for (int nt = 0; nt < NTW; ++nt)
          Cout[ob + nt * 16] = f2bf(acc[m][nt][r]);
      }
    }

#pragma unroll
  for (int nt = 0; nt < NTW; ++nt) {
    float s = 0.f, q = 0.f;
#pragma unroll
    for (int m = 0; m < 4; ++m)
#pragma unroll
      for (int r = 0; r < 4; ++r) {
        float vv = acc[m][nt][r];          // invalid rows are 0 (A zeroed)
        s += vv; q += vv * vv;
      }
    s += __shfl_xor(s, 16); s += __shfl_xor(s, 32);
    q += __shfl_xor(q, 16); q += __shfl_xor(q, 32);
    if (quad == 0) {
      int col = n0 + nt * 16 + l15;
      atomicAdd(stats + col, s);
      atomicAdd(stats + KO + col, q);
    }
  }
}

// ---------- BN finalize ----------
__global__ void bn_finalize(const float* __restrict__ sums, const void* __restrict__ g,
                            const void* __restrict__ b, const int* __restrict__ flags,
                            float* __restrict__ ss, int Ko) {
  int c = blockIdx.x * blockDim.x + threadIdx.x;
  if (c < Ko) {
    const float invN = 1.f / (float)NN;
    float mu = sums[c] * invN;
    float var = sums[Ko + c] * invN - mu * mu;
    float sc = load1f(g, c, flags[0]) * rsqrtf(var + 1e-5f);
    ss[c] = sc;
    ss[Ko + c] = load1f(b, c, flags[0]) - mu * sc;
  }
}

// ---------- relu(bn(u)) -> bf16 X, optional row mask-zeroing; u is bf16 ----------
template<bool MASKED>
__launch_bounds__(256)
__global__ void bnrelu_ew(const unsigned short* __restrict__ in, const float* __restrict__ ss,
                          const void* __restrict__ maskp, const int* __restrict__ flags,
                          unsigned short* __restrict__ out, int Ko) {
  int idx = blockIdx.x * 256 + threadIdx.x;
  int total = NN * (Ko / 4);
  if (idx >= total) return;
  int row = idx / (Ko / 4);
  int j = (idx % (Ko / 4)) * 4;
  ushort4 h = *(const ushort4*)(in + (size_t)idx * 4);
  float4 o;
  o.x = fmaxf(0.f, bf2f(h.x) * ss[j]     + ss[Ko + j]);
  o.y = fmaxf(0.f, bf2f(h.y) * ss[j + 1] + ss[Ko + j + 1]);
  o.z = fmaxf(0.f, bf2f(h.z) * ss[j + 2] + ss[Ko + j + 2]);
  o.w = fmaxf(0.f, bf2f(h.w) * ss[j + 3] + ss[Ko + j + 3]);
  if (MASKED && maskAt(maskp, row, flags[1])) o = make_float4(0.f, 0.f, 0.f, 0.f);
  ushort4 b4; b4.x = f2bf(o.x); b4.y = f2bf(o.y); b4.z = f2bf(o.z); b4.w = f2bf(o.w);
  *(ushort4*)(out + (size_t)idx * 4) = b4;
}

// ---------- recon loss: one row per wave, channel-spread binned atomics ----------
// accb layout: sum at accb[bin*16], cnt at accb[1024 + bin*16]
__launch_bounds__(256)
__global__ void loss_kernel(const unsigned short* __restrict__ u2, const float* __restrict__ ss,
                            const void* __restrict__ xp, const void* __restrict__ maskp,
                            const int* __restrict__ flags,
                            unsigned short* __restrict__ rx, float* __restrict__ accb) {
  __shared__ float redS[4], redC[4];
  int r = (blockIdx.x * 256 + threadIdx.x) >> 6;
  int lane = threadIdx.x & 63;
  int wv = threadIdx.x >> 6;
  int fbf = flags[0], mu8 = flags[1];
  float lsum = 0.f, lcnt = 0.f;
  if (r < NN) {
    size_t b0 = (size_t)r * 128;
    int c0 = 2 * lane, c1 = 2 * lane + 1;
    ushort2 uh = *(const ushort2*)(u2 + b0 + c0);
    float a0 = fmaxf(0.f, bf2f(uh.x) * ss[c0] + ss[128 + c0]);
    float a1 = fmaxf(0.f, bf2f(uh.y) * ss[c1] + ss[128 + c1]);
    float x0, x1;
    if (fbf) {
      ushort2 xh = *(const ushort2*)((const unsigned short*)xp + b0 + c0);
      x0 = bf2f(xh.x); x1 = bf2f(xh.y);
    } else {
      float2 xf = *(const float2*)((const float*)xp + b0 + c0);
      x0 = xf.x; x1 = xf.y;
    }
    ushort2 o; o.x = f2bf(a0); o.y = f2bf(a1);
    *(ushort2*)(rx + b0 + c0) = o;
    float dot = a0 * x0 + a1 * x1;
    float na = a0 * a0 + a1 * a1;
    float nx = x0 * x0 + x1 * x1;
#pragma unroll
    for (int off = 32; off > 0; off >>= 1) {
      dot += __shfl_xor(dot, off);
      na  += __shfl_xor(na, off);
      nx  += __shfl_xor(nx, off);
    }
    float cs = dot / (fmaxf(sqrtf(na), 1e-12f) * fmaxf(sqrtf(nx), 1e-12f));
    if (maskAt(maskp, r, mu8)) { lsum = 1.f - cs; lcnt = 1.f; }
  }
  if (lane == 0) { redS[wv] = lsum; redC[wv] = lcnt; }
  __syncthreads();
  if (threadIdx.x == 0) {
    float s = redS[0] + redS[1] + redS[2] + redS[3];
    float c = redC[0] + redC[1] + redC[2] + redC[3];
    int bin = (blockIdx.x & 63) * 16;
    atomicAdd(&accb[bin], s);
    atomicAdd(&accb[1024 + bin], c);
  }
}

// ---------- contrastive: one row per wave, channel-spread binned atomics ----------
__launch_bounds__(256)
__global__ void cl_kernel(const unsigned short* __restrict__ r1,
                          const unsigned short* __restrict__ r2,
                          float* __restrict__ accb) {
  __shared__ float redS[4];
  int r = (blockIdx.x * 256 + threadIdx.x) >> 6;
  int lane = threadIdx.x & 63;
  int wv = threadIdx.x >> 6;
  float lsum = 0.f;
  if (r < NN) {
    size_t b0 = (size_t)r * 128;
    int c0 = 2 * lane;
    ushort2 h1 = *(const ushort2*)(r1 + b0 + c0);
    ushort2 h2 = *(const ushort2*)(r2 + b0 + c0);
    float a0 = bf2f(h1.x), a1 = bf2f(h1.y);
    float c0v = bf2f(h2.x), c1v = bf2f(h2.y);
    float dot = a0 * c0v + a1 * c1v;
    float na = a0 * a0 + a1 * a1;
    float nb = c0v * c0v + c1v * c1v;
#pragma unroll
    for (int off = 32; off > 0; off >>= 1) {
      dot += __shfl_xor(dot, off);
      na  += __shfl_xor(na, off);
      nb  += __shfl_xor(nb, off);
    }
    float cs = dot / (fmaxf(sqrtf(na), 1e-12f) * fmaxf(sqrtf(nb), 1e-12f));
    lsum = 1.f - cs;
  }
  if (lane == 0) redS[wv] = lsum;
  __syncthreads();
  if (threadIdx.x == 0) {
    float s = redS[0] + redS[1] + redS[2] + redS[3];
    atomicAdd(&accb[(blockIdx.x & 63) * 16], s);
  }
}

// ---------- final: reduce 64-bin accumulators (stride-16) ----------
// groups: 0=l1sum, 1024=l1cnt, 2048=l2sum, 3072=l2cnt, 4096=cl
__global__ void final_kernel(const float* __restrict__ acc, void* __restrict__ out,
                             const int* __restrict__ flags) {
  int lane = threadIdx.x & 63;
  float v0 = acc[lane * 16], v1 = acc[1024 + lane * 16], v2 = acc[2048 + lane * 16];
  float v3 = acc[3072 + lane * 16], v4 = acc[4096 + lane * 16];
#pragma unroll
  for (int off = 32; off > 0; off >>= 1) {
    v0 += __shfl_xor(v0, off);
    v1 += __shfl_xor(v1, off);
    v2 += __shfl_xor(v2, off);
    v3 += __shfl_xor(v3, off);
    v4 += __shfl_xor(v4, off);
  }
  if (threadIdx.x == 0 && blockIdx.x == 0) {
    float v = v0 / v1 + v2 / v3 + 0.1f * (v4 / (float)NN);
    if (flags[0]) ((unsigned short*)out)[0] = f2bf(v);
    else          ((float*)out)[0] = v;
  }
}

extern "C" void kernel_launch(void* const* d_in, const int* in_sizes, int n_in,
                              void* d_out, int out_size, void* d_ws, size_t ws_size,
                              hipStream_t stream) {
  const void* x   = d_in[0];
  const void* ei1 = d_in[1];
  const void* ei2 = d_in[2];
  const void* m1  = d_in[3];
  const void* m2  = d_in[4];
  const void* e0_w1 = d_in[6],  *e0_w2 = d_in[7],  *e0_bg = d_in[8],  *e0_bb = d_in[9];
  const void* e0_ng = d_in[10], *e0_nb = d_in[11];
  const void* e1_w1 = d_in[12], *e1_w2 = d_in[13], *e1_bg = d_in[14], *e1_bb = d_in[15];
  const void* e1_ng = d_in[16], *e1_nb = d_in[17];
  const void* dw1 = d_in[18], *dw2 = d_in[19], *dbg = d_in[20], *dbb = d_in[21];
  const void* dng = d_in[22], *dnb = d_in[23];

  // ---- workspace layout ----
  char* p = (char*)d_ws;
  const size_t OFS_T      = 0;                                    // bf16 N*512
  const size_t OFS_AGG    = OFS_T      + (size_t)NN * 512 * 2;    // bf16 N*256 (aliased as u)
  const size_t OFS_X      = OFS_AGG    + (size_t)NN * 256 * 2;    // bf16 N*256
  const size_t OFS_RX1    = OFS_X      + (size_t)NN * 256 * 2;    // bf16 N*128
  const size_t OFS_RX2    = OFS_RX1    + (size_t)NN * 128 * 2;
  const size_t OFS_WT     = OFS_RX2    + (size_t)NN * 128 * 2;    // bf16 655360
  const size_t OFS_ROWPTR = OFS_WT     + 655360 * 2;              // int 50016
  const size_t OFS_CURSOR = OFS_ROWPTR + 50016 * 4;               // int 50016
  const size_t OFS_ADJ    = OFS_CURSOR + 50016 * 4;               // int NEDGE
  const size_t OFS_BSUM   = OFS_ADJ    + (size_t)NEDGE * 4;       // int 256
  const size_t OFS_STATS  = OFS_BSUM   + 256 * 4;                 // f 1024
  const size_t OFS_SS     = OFS_STATS  + 1024 * 4;                // f 1024
  const size_t OFS_ACC    = OFS_SS     + 1024 * 4;                // f 5120 (binned, stride16)
  const size_t OFS_FLAGS  = OFS_ACC    + 5120 * 4;                // i 4
  const size_t NEED       = OFS_FLAGS + 16;

  if (ws_size < NEED) {
    diag_kernel<<<1, 64, 0, stream>>>(d_out, (float)(ws_size >> 20));
    return;
  }

  unsigned short* T   = (unsigned short*)(p + OFS_T);
  unsigned short* AGG = (unsigned short*)(p + OFS_AGG);
  unsigned short* U   = AGG;   // alias: agg dead once g2 writes u
  unsigned short* X   = (unsigned short*)(p + OFS_X);
  unsigned short* RX1 = (unsigned short*)(p + OFS_RX1);
  unsigned short* RX2 = (unsigned short*)(p + OFS_RX2);
  unsigned short* WT  = (unsigned short*)(p + OFS_WT);
  int* rowptr = (int*)(p + OFS_ROWPTR);
  int* cursor = (int*)(p + OFS_CURSOR);
  int* adj    = (int*)(p + OFS_ADJ);
  int* bsum   = (int*)(p + OFS_BSUM);
  float* stats = (float*)(p + OFS_STATS);
  float* ss    = (float*)(p + OFS_SS);
  float* acc   = (float*)(p + OFS_ACC);
  int*   flags = (int*)(p + OFS_FLAGS);

  const int EB = (NEDGE + 255) / 256;        // 1250
  const int SB = (NN + 255) / 256;           // 196
  const int GB = (NN + 63) / 64;             // 782 row-blocks
  const int WB = (NN + 3) / 4;               // 12500 blocks (1 node/wave)
  const dim3 gS2(GB, 2), gS1(GB, 1);

  hipMemsetAsync(acc, 0, 5120 * sizeof(float) + 4 * sizeof(int), stream);
  sniff_kernel<<<1, 64, 0, stream>>>(e0_bg, m1, ei1, flags);

  // weight transposes (once; bf16)
  transpose_w<<<(128 * 512 + 255) / 256, 256, 0, stream>>>(e0_w1, flags, WT + 0,      128, 512);
  transpose_w<<<(512 * 256 + 255) / 256, 256, 0, stream>>>(e0_w2, flags, WT + 65536,  512, 256);
  transpose_w<<<(256 * 512 + 255) / 256, 256, 0, stream>>>(e1_w1, flags, WT + 196608, 256, 512);
  transpose_w<<<(512 * 256 + 255) / 256, 256, 0, stream>>>(e1_w2, flags, WT + 327680, 512, 256);
  transpose_w<<<(256 * 512 + 255) / 256, 256, 0, stream>>>(dw1,   flags, WT + 458752, 256, 512);
  transpose_w<<<(512 * 128 + 255) / 256, 256, 0, stream>>>(dw2,   flags, WT + 589824, 512, 128);

  for (int pass = 0; pass < 2; ++pass) {
    const void* ei = pass ? ei2 : ei1;
    const void* mk = pass ? m2 : m1;
    unsigned short* rx = pass ? RX2 : RX1;
    float* accp = acc + 2048 * pass;

    // ---- CSR build ----
    hipMemsetAsync(cursor, 0, 50016 * 4, stream);
    csr_hist<<<EB, 256, 0, stream>>>(ei, flags, cursor);
    scan1<<<SB, 256, 0, stream>>>(cursor, rowptr, bsum);
    scan2<<<1, 256, 0, stream>>>(bsum, SB);
    scan3<<<SB, 256, 0, stream>>>(rowptr, bsum, cursor);
    csr_fill<<<EB, 256, 0, stream>>>(ei, flags, cursor, adj);

    // ---- encoder L0 (128 -> 512 -> 256) ----
    gather_k<128, true><<<WB, 256, 0, stream>>>(x, K_IN, mk, rowptr, adj, flags, AGG);
    hipMemsetAsync(stats, 0, 1024 * 4, stream);
    gemm_mfma<128, 512, 2, true, true, false><<<gS2, 256, 0, stream>>>(
        x, K_IN, AGG, mk, nullptr, WT + 0, T, stats, flags);
    bn_finalize<<<2, 256, 0, stream>>>(stats, e0_bg, e0_bb, flags, ss, 512);
    hipMemsetAsync(stats, 0, 512 * 4, stream);
    gemm_mfma<512, 256, 2, false, false, true><<<gS2, 256, 0, stream>>>(
        T, K_BF16, nullptr, nullptr, ss, WT + 65536, U, stats, flags);
    bn_finalize<<<1, 256, 0, stream>>>(stats, e0_ng, e0_nb, flags, ss, 256);
    bnrelu_ew<false><<<12500, 256, 0, stream>>>(U, ss, nullptr, flags, X, 256);

    // ---- encoder L1 (256 -> 512 -> 256) ----
    gather_k<256, false><<<WB, 256, 0, stream>>>(X, K_BF16, nullptr, rowptr, adj, flags, AGG);
    hipMemsetAsync(stats, 0, 1024 * 4, stream);
    gemm_mfma<256, 512, 2, false, true, false><<<gS2, 256, 0, stream>>>(
        X, K_BF16, AGG, nullptr, nullptr, WT + 196608, T, stats, flags);
    bn_finalize<<<2, 256, 0, stream>>>(stats, e1_bg, e1_bb, flags, ss, 512);
    hipMemsetAsync(stats, 0, 512 * 4, stream);
    gemm_mfma<512, 256, 2, false, false, true><<<gS2, 256, 0, stream>>>(
        T, K_BF16, nullptr, nullptr, ss, WT + 327680, U, stats, flags);
    bn_finalize<<<1, 256, 0, stream>>>(stats, e1_ng, e1_nb, flags, ss, 256);
    bnrelu_ew<true><<<12500, 256, 0, stream>>>(U, ss, mk, flags, X, 256);   // re_h (masked)

    // ---- decoder (256 -> 512 -> 128) ----
    gather_k<256, false><<<WB, 256, 0, stream>>>(X, K_BF16, nullptr, rowptr, adj, flags, AGG);
    hipMemsetAsync(stats, 0, 1024 * 4, stream);
    gemm_mfma<256, 512, 2, false, true, false><<<gS2, 256, 0, stream>>>(
        X, K_BF16, AGG, nullptr, nullptr, WT + 458752, T, stats, flags);
    bn_finalize<<<2, 256, 0, stream>>>(stats, dbg, dbb, flags, ss, 512);
    hipMemsetAsync(stats, 0, 256 * 4, stream);
    gemm_mfma<512, 128, 1, false, false, true><<<gS1, 256, 0, stream>>>(
        T, K_BF16, nullptr, nullptr, ss, WT + 589824, U, stats, flags);
    bn_finalize<<<1, 256, 0, stream>>>(stats, dng, dnb, flags, ss, 128);

    loss_kernel<<<WB, 256, 0, stream>>>(U, ss, x, mk, flags, rx, accp);
  }

  cl_kernel<<<WB, 256, 0, stream>>>(RX1, RX2, acc + 4096);
  final_kernel<<<1, 64, 0, stream>>>(acc, d_out, flags);
}